// Round 16
// baseline (521.042 us; speedup 1.0000x reference)
//
#include <hip/hip_runtime.h>
#include <cstdint>

typedef __attribute__((ext_vector_type(8))) short short8;
typedef __attribute__((ext_vector_type(4))) float f32x4;

__device__ __forceinline__ ushort f2bf(float x){
    uint32_t u = __float_as_uint(x);
    u = (u + 0x7FFFu + ((u >> 16) & 1u)) >> 16;
    return (ushort)u;
}
__device__ __forceinline__ ushort f2h(float x){
    _Float16 h = (_Float16)x;
    return __builtin_bit_cast(ushort, h);
}

// -------- kernel 1: weight conversion (fp16 W + W1, bf16 W2 + embed) ------
__global__ void k_conv(const float* __restrict__ W1, const float* __restrict__ W2,
                       const float* __restrict__ Emb, const float* __restrict__ W,
                       ushort* __restrict__ W1h, ushort* __restrict__ W2b,
                       ushort* __restrict__ Eb, ushort* __restrict__ Wh){
    int i = blockIdx.x * 256 + threadIdx.x;   // grid 256 -> 65536
    W1h[i] = f2h(W1[i]);
    W2b[i] = f2bf(W2[i]);
    Eb[i]  = f2bf(Emb[i]);
    Wh[i]  = f2h(W[i]);
}

// -------- kernel 2: proj[v][h] = sum_e embed[v,e]*W_in[h,e]  (fp32) -------
__global__ void k_proj(const float* __restrict__ emb, const float* __restrict__ Win,
                       float* __restrict__ proj){
    __shared__ __align__(16) float se[256];
    int v = blockIdx.x, h = threadIdx.x;
    se[h] = emb[v*256 + h];
    __syncthreads();
    const float* wr = Win + h*256;
    float a0=0.f,a1=0.f,a2=0.f,a3=0.f;
    #pragma unroll
    for (int e = 0; e < 256; e += 4){
        float4 w = *(const float4*)(wr + e);
        a0 = fmaf(w.x, se[e+0], a0);
        a1 = fmaf(w.y, se[e+1], a1);
        a2 = fmaf(w.z, se[e+2], a2);
        a3 = fmaf(w.w, se[e+3], a3);
    }
    proj[v*256 + h] = (a0+a1)+(a2+a3);
}

// ------------- kernel 3: ESN recurrence via MFMA, fp16 W+state ------------
// 256 blocks = (segment s in [0,32)) x (batch group pg in [0,8)), 1 block/CU.
// Segment s writes t in [64s, 64s+64); s>0 starts from h=0 at
// t0 = max(0, 64s-128); warmup=128 HW-verified (rounds 13/14, absmax at
// fp16 floor). Critical path 192 steps @ ~676ns/step (round 14: ~130us).
__global__ __launch_bounds__(512, 2) void k_recur(const int* __restrict__ idx,
        const ushort* Wh, const float* proj, ushort* hs){
    __shared__ __align__(16) char Hl[2][8192];   // fp16 H[16][256], dbuf, swizzled
    const int tid  = threadIdx.x;
    const int wid  = tid >> 6;
    const int lane = tid & 63;
    const int lr   = lane & 15;        // batch col / A-row-in-tile
    const int lg   = lane >> 4;
    const int seg  = blockIdx.x >> 3;  // time segment 0..31
    const int pg   = blockIdx.x & 7;   // batch group 0..7
    const int t0   = (64*seg - 128 > 0) ? (64*seg - 128) : 0;
    const int t1   = 64*seg + 64;
    const int tw   = 64*seg;           // first written step

    // A-frags: W rows for tiles n0=2*wid, n1=2*wid+1 (fp16, 16 frags = 64 VGPR)
    short8 A0[8], A1[8];
    {
        const char* wb = (const char*)Wh + (32*wid + lr)*512 + lg*16;
        #pragma unroll
        for (int kk = 0; kk < 8; ++kk){
            A0[kk] = __builtin_bit_cast(short8, *(const uint4*)(wb + kk*64));
            A1[kk] = __builtin_bit_cast(short8, *(const uint4*)(wb + 16*512 + kk*64));
        }
    }

    char* Hb = &Hl[0][0];
    *(uint4*)(Hb + tid*16) = uint4{0,0,0,0};     // zero buffer 0 (8 KB)
    __syncthreads();

    const int mybat = pg*16 + lr;
    const int64_t idxbase = (int64_t)mybat * 2048;
    ushort* hsrow = hs + (size_t)mybat * 2048 * 256;
    const int hd0 = 32*wid + lg*4;               // tile0 quad base hdim
    const int hd1 = hd0 + 16;

    float hp0[4] = {0.f,0.f,0.f,0.f}, hp1[4] = {0.f,0.f,0.f,0.f};

    // prologue: u for t0, token for t0+1
    int tok  = idx[idxbase + t0];
    int tok2 = idx[idxbase + ((t0+1 < 2048) ? t0+1 : 2047)];
    f32x4 u0 = *(const f32x4*)(proj + tok*256 + hd0);
    f32x4 u1 = *(const f32x4*)(proj + tok*256 + hd1);

#define STEP(T, RO, WO)                                                        \
    {                                                                          \
        int tok3 = idx[idxbase + (((T)+2 < 2048) ? (T)+2 : 2047)];             \
        f32x4 ac0 = u0, ac1 = u1;   /* C-init = input projection */            \
        f32x4 bc0 = {0.f,0.f,0.f,0.f}, bc1 = {0.f,0.f,0.f,0.f};                \
        _Pragma("unroll")                                                      \
        for (int kk = 0; kk < 4; ++kk){                                        \
            int ra = ((RO) + lr*512 + kk*64 + lg*16) ^ (lr << 4);              \
            short8 Bf = __builtin_bit_cast(short8, *(const uint4*)(Hb + ra));  \
            ac0 = __builtin_amdgcn_mfma_f32_16x16x32_f16(A0[kk], Bf, ac0, 0,0,0);\
            ac1 = __builtin_amdgcn_mfma_f32_16x16x32_f16(A1[kk], Bf, ac1, 0,0,0);\
        }                                                                      \
        _Pragma("unroll")                                                      \
        for (int kk = 4; kk < 8; ++kk){                                        \
            int ra = ((RO) + lr*512 + kk*64 + lg*16) ^ (lr << 4);              \
            short8 Bf = __builtin_bit_cast(short8, *(const uint4*)(Hb + ra));  \
            bc0 = __builtin_amdgcn_mfma_f32_16x16x32_f16(A0[kk], Bf, bc0, 0,0,0);\
            bc1 = __builtin_amdgcn_mfma_f32_16x16x32_f16(A1[kk], Bf, bc1, 0,0,0);\
        }                                                                      \
        f32x4 u0n = *(const f32x4*)(proj + tok2*256 + hd0);                    \
        f32x4 u1n = *(const f32x4*)(proj + tok2*256 + hd1);                    \
        float hn0[4], hn1[4];                                                  \
        _Pragma("unroll")                                                      \
        for (int q = 0; q < 4; ++q){                                           \
            float p0 = ac0[q] + bc0[q];                                        \
            float e0 = __builtin_amdgcn_exp2f(p0 * 2.8853900817779268f);       \
            float r0 = __builtin_amdgcn_rcpf(e0 + 1.f);                        \
            hn0[q] = fmaf(0.7f, hp0[q], fmaf(-0.6f, r0, 0.3f));                \
            hp0[q] = hn0[q];                                                   \
            float p1 = ac1[q] + bc1[q];                                        \
            float e1 = __builtin_amdgcn_exp2f(p1 * 2.8853900817779268f);       \
            float r1 = __builtin_amdgcn_rcpf(e1 + 1.f);                        \
            hn1[q] = fmaf(0.7f, hp1[q], fmaf(-0.6f, r1, 0.3f));                \
            hp1[q] = hn1[q];                                                   \
        }                                                                      \
        uint2 pk0, pk1;                                                        \
        pk0.x = __builtin_bit_cast(uint, __builtin_amdgcn_cvt_pkrtz(hn0[0], hn0[1])); \
        pk0.y = __builtin_bit_cast(uint, __builtin_amdgcn_cvt_pkrtz(hn0[2], hn0[3])); \
        pk1.x = __builtin_bit_cast(uint, __builtin_amdgcn_cvt_pkrtz(hn1[0], hn1[1])); \
        pk1.y = __builtin_bit_cast(uint, __builtin_amdgcn_cvt_pkrtz(hn1[2], hn1[3])); \
        int wa0 = ((WO) + lr*512 + hd0*2) ^ (lr << 4);                         \
        int wa1 = ((WO) + lr*512 + hd1*2) ^ (lr << 4);                         \
        *(uint2*)(Hb + wa0) = pk0;                                             \
        *(uint2*)(Hb + wa1) = pk1;                                             \
        if ((T) >= tw){                                                        \
            *(uint2*)(hsrow + (size_t)(T)*256 + hd0) = pk0;                    \
            *(uint2*)(hsrow + (size_t)(T)*256 + hd1) = pk1;                    \
        }                                                                      \
        u0 = u0n; u1 = u1n; tok2 = tok3;                                       \
        asm volatile("s_waitcnt lgkmcnt(0)\n\ts_barrier" ::: "memory");        \
    }

    for (int t = t0; t < t1; t += 2){
        STEP(t,   0,    8192);
        STEP(t+1, 8192, 0);
    }
#undef STEP
}

// ---------------- kernel 4: fused readout MLP + LN + lm_head --------------
// 2048 blocks x 128 BT-rows (round 15 falsified 64-row blocks: doubled
// weight re-staging + split HBM writes). T14 pipelined staging: 64-row
// weight chunks double-buffered in w_lds[2][32KB]; each phase issues the
// NEXT chunk's global loads into regs BEFORE its MFMAs (latency hides under
// MFMA; barrier drain lands post-MFMA), then writes regs->LDS after the
// consumption barrier. 12 phases. 8 waves = (mg 0..3) x (ng 0..1): wave
// owns 2 m-tiles x 2 n-tiles/chunk -> wfrag 1-read:2-MFMA preserved.
// GEMM3 in SWAPPED form -> each lane stores one float4 (coalesced quads).
__global__ __launch_bounds__(512, 2) void k_readout(
        const ushort* __restrict__ hs,
        const ushort* __restrict__ W1h, const ushort* __restrict__ W2b,
        const ushort* __restrict__ Eb,
        const float* __restrict__ b1, const float* __restrict__ b2,
        const float* __restrict__ gamma, const float* __restrict__ beta,
        float* __restrict__ out){
    __shared__ __align__(16) char w_lds[2][32768]; // 64-row weight chunk, dbuf
    __shared__ __align__(16) char a_lds[65536];    // A1 / y tile: 128 x 256 x 2B
    __shared__ __align__(16) float4 ln_lds[8][16]; // LN partials per (wave, lr)

    const int tid  = threadIdx.x;
    const int wid  = tid >> 6;
    const int mg   = wid >> 1;                    // 0..3: rows 32mg..32mg+32
    const int ng   = wid & 1;                     // n-half within chunk
    const int lane = tid & 63;
    const int lr   = lane & 15;
    const int lg   = lane >> 4;
    const size_t m0 = (size_t)blockIdx.x * 128;
    const int ml0  = mg*32 + lr;
    const int ml1  = ml0 + 16;

    uint4 st[4];                                   // staged chunk in regs
    auto load_chunk = [&](const ushort* src){
        #pragma unroll
        for (int i = 0; i < 4; ++i)
            st[i] = *(const uint4*)((const char*)src + (i*512 + tid)*16);
    };
    auto write_chunk = [&](int buf){
        #pragma unroll
        for (int i = 0; i < 4; ++i){
            int off = (i*512 + tid)*16;
            int row = off >> 9;
            *(uint4*)(&w_lds[buf][0] + (off ^ ((row & 7) << 4))) = st[i];
        }
    };
    // A-fragment of staged chunk: row nt*16+lr (nt 0..3), k-chunk k0
    auto wfrag = [&](int buf, int nt, int k0) -> short8 {
        int row  = nt*16 + lr;
        int addr = (row << 9) + k0*64 + lg*16;
        addr ^= (row & 7) << 4;
        return __builtin_bit_cast(short8, *(const uint4*)(&w_lds[buf][0] + addr));
    };
    auto afrag = [&](int ml, int k0) -> short8 {
        int addr = (ml << 9) + k0*64 + lg*16;
        addr ^= (ml & 7) << 4;
        return __builtin_bit_cast(short8, *(const uint4*)(a_lds + addr));
    };
    auto awrite = [&](int ml, int ecol, f32x4 v){
        ushort4 pk;
        pk.x = f2bf(v[0]); pk.y = f2bf(v[1]); pk.z = f2bf(v[2]); pk.w = f2bf(v[3]);
        int addr = (ml << 9) + ecol*2;
        addr ^= (ml & 7) << 4;
        *(ushort4*)(a_lds + addr) = pk;
    };

    // ---- hs fragments for both m-tiles (fp16, 16B/lane) ----
    short8 hb0[8], hb1[8];
    {
        const char* p0 = (const char*)(hs + (m0 + ml0)*256) + lg*16;
        const char* p1 = (const char*)(hs + (m0 + ml1)*256) + lg*16;
        #pragma unroll
        for (int k0 = 0; k0 < 8; ++k0){
            hb0[k0] = __builtin_bit_cast(short8, *(const uint4*)(p0 + k0*64));
            hb1[k0] = __builtin_bit_cast(short8, *(const uint4*)(p1 + k0*64));
        }
    }

    load_chunk(W1h);          // chunk 0
    write_chunk(0);
    __syncthreads();

    // ============ GEMM1 (fp16): A1 = gelu(hs @ W1.T + b1), 4 chunks ============
    #pragma unroll
    for (int c = 0; c < 4; ++c){
        load_chunk(c < 3 ? (W1h + (c+1)*16384) : W2b);   // issue next early
        #pragma unroll
        for (int n = 0; n < 2; ++n){
            int nt  = ng*2 + n;
            int ebn = c*64 + nt*16;
            float4 bi = *(const float4*)(b1 + ebn + lg*4);
            f32x4 acc0 = {bi.x, bi.y, bi.z, bi.w};
            f32x4 acc1 = acc0;
            #pragma unroll
            for (int k0 = 0; k0 < 8; ++k0){
                short8 wf = wfrag(c & 1, nt, k0);
                acc0 = __builtin_amdgcn_mfma_f32_16x16x32_f16(wf, hb0[k0], acc0, 0,0,0);
                acc1 = __builtin_amdgcn_mfma_f32_16x16x32_f16(wf, hb1[k0], acc1, 0,0,0);
            }
            f32x4 g0, g1;
            #pragma unroll
            for (int q = 0; q < 4; ++q){
                float x = acc0[q];
                g0[q] = 0.5f*x*(1.f + erff(x*0.70710678118654752440f));
                x = acc1[q];
                g1[q] = 0.5f*x*(1.f + erff(x*0.70710678118654752440f));
            }
            awrite(ml0, ebn + lg*4, g0);
            awrite(ml1, ebn + lg*4, g1);
        }
        __syncthreads();
        write_chunk((c & 1) ^ 1);
        __syncthreads();
    }

    // ============ GEMM2 (bf16): o = A1 @ W2.T + b2, 4 chunks ============
    short8 ab0[8], ab1[8];
    f32x4 o0[8], o1[8];
    #pragma unroll
    for (int c = 0; c < 4; ++c){
        load_chunk(c < 3 ? (W2b + (c+1)*16384) : Eb);
        if (c == 0){
            #pragma unroll
            for (int k0 = 0; k0 < 8; ++k0){ ab0[k0] = afrag(ml0, k0); ab1[k0] = afrag(ml1, k0); }
        }
        #pragma unroll
        for (int n = 0; n < 2; ++n){
            int nt  = ng*2 + n;
            int ebn = c*64 + nt*16;
            float4 bi = *(const float4*)(b2 + ebn + lg*4);
            f32x4 acc0 = {bi.x, bi.y, bi.z, bi.w};
            f32x4 acc1 = acc0;
            #pragma unroll
            for (int k0 = 0; k0 < 8; ++k0){
                short8 wf = wfrag(c & 1, nt, k0);
                acc0 = __builtin_amdgcn_mfma_f32_16x16x32_bf16(wf, ab0[k0], acc0, 0,0,0);
                acc1 = __builtin_amdgcn_mfma_f32_16x16x32_bf16(wf, ab1[k0], acc1, 0,0,0);
            }
            o0[c*2+n] = acc0;
            o1[c*2+n] = acc1;
        }
        __syncthreads();
        write_chunk((c & 1) ^ 1);
        __syncthreads();
    }

    // ====== LayerNorm over e2: in-wave shfl + cross-wave (ng pair) LDS ======
    {
        float s0 = 0.f, q0 = 0.f, s1 = 0.f, q1 = 0.f;
        #pragma unroll
        for (int i = 0; i < 8; ++i){
            #pragma unroll
            for (int q = 0; q < 4; ++q){
                float x = o0[i][q]; s0 += x; q0 += x*x;
                float y = o1[i][q]; s1 += y; q1 += y*y;
            }
        }
        s0 += __shfl_xor(s0, 16); q0 += __shfl_xor(q0, 16);
        s0 += __shfl_xor(s0, 32); q0 += __shfl_xor(q0, 32);
        s1 += __shfl_xor(s1, 16); q1 += __shfl_xor(q1, 16);
        s1 += __shfl_xor(s1, 32); q1 += __shfl_xor(q1, 32);
        if (lg == 0) ln_lds[wid][lr] = float4{s0, q0, s1, q1};
        __syncthreads();
        float4 pp = ln_lds[wid ^ 1][lr];
        s0 += pp.x; q0 += pp.y; s1 += pp.z; q1 += pp.w;
        float mu0   = s0 * (1.f/256.f);
        float var0  = q0 * (1.f/256.f) - mu0*mu0;
        float rstd0 = rsqrtf(var0 + 1e-5f);
        float mu1   = s1 * (1.f/256.f);
        float var1  = q1 * (1.f/256.f) - mu1*mu1;
        float rstd1 = rsqrtf(var1 + 1e-5f);
        #pragma unroll
        for (int i = 0; i < 8; ++i){
            int c = i >> 1, n = i & 1;
            int ecol = c*64 + (ng*2 + n)*16 + lg*4;
            float4 g4 = *(const float4*)(gamma + ecol);
            float4 t4 = *(const float4*)(beta + ecol);
            f32x4 y0, y1;
            y0[0] = (o0[i][0]-mu0)*rstd0*g4.x + t4.x;
            y0[1] = (o0[i][1]-mu0)*rstd0*g4.y + t4.y;
            y0[2] = (o0[i][2]-mu0)*rstd0*g4.z + t4.z;
            y0[3] = (o0[i][3]-mu0)*rstd0*g4.w + t4.w;
            y1[0] = (o1[i][0]-mu1)*rstd1*g4.x + t4.x;
            y1[1] = (o1[i][1]-mu1)*rstd1*g4.y + t4.y;
            y1[2] = (o1[i][2]-mu1)*rstd1*g4.z + t4.z;
            y1[3] = (o1[i][3]-mu1)*rstd1*g4.w + t4.w;
            awrite(ml0, ecol, y0);
            awrite(ml1, ecol, y1);
        }
    }
    __syncthreads();

    // ===== GEMM3 (bf16, SWAPPED): logits D[v,m] -> float4 stores =====
    #pragma unroll
    for (int k0 = 0; k0 < 8; ++k0){ ab0[k0] = afrag(ml0, k0); ab1[k0] = afrag(ml1, k0); }
    #pragma unroll
    for (int c = 0; c < 4; ++c){
        if (c < 3) load_chunk(Eb + (c+1)*16384);
        #pragma unroll
        for (int n = 0; n < 2; ++n){
            int nt = ng*2 + n;
            f32x4 acc0 = {0.f,0.f,0.f,0.f};
            f32x4 acc1 = acc0;
            #pragma unroll
            for (int k0 = 0; k0 < 8; ++k0){
                short8 wf = wfrag(c & 1, nt, k0);
                acc0 = __builtin_amdgcn_mfma_f32_16x16x32_bf16(wf, ab0[k0], acc0, 0,0,0);
                acc1 = __builtin_amdgcn_mfma_f32_16x16x32_bf16(wf, ab1[k0], acc1, 0,0,0);
            }
            int vb = c*64 + nt*16 + lg*4;          // 4 consecutive vocab cols
            *(f32x4*)(out + (m0 + mg*32 + lr)*256 + vb)      = acc0;
            *(f32x4*)(out + (m0 + mg*32 + 16 + lr)*256 + vb) = acc1;
        }
        if (c < 3){
            __syncthreads();
            write_chunk((c & 1) ^ 1);
            __syncthreads();
        }
    }
}

// --------------------------------------------------------------------------
extern "C" void kernel_launch(void* const* d_in, const int* in_sizes, int n_in,
                              void* d_out, int out_size, void* d_ws, size_t ws_size,
                              hipStream_t stream){
    const int*   idx   = (const int*)d_in[0];
    const float* embed = (const float*)d_in[1];
    const float* W_in  = (const float*)d_in[2];
    const float* W     = (const float*)d_in[3];
    const float* W1    = (const float*)d_in[4];
    const float* b1    = (const float*)d_in[5];
    const float* W2    = (const float*)d_in[6];
    const float* b2    = (const float*)d_in[7];
    const float* gamma = (const float*)d_in[8];
    const float* beta  = (const float*)d_in[9];

    char* ws = (char*)d_ws;
    float*  proj  = (float*)ws;                   // 256 KB fp32
    ushort* W1h   = (ushort*)(ws + 262144);       // 128 KB fp16
    ushort* W2b   = (ushort*)(ws + 393216);       // 128 KB bf16
    ushort* Eb    = (ushort*)(ws + 524288);       // 128 KB bf16
    ushort* Wh    = (ushort*)(ws + 655360);       // 128 KB fp16 W
    ushort* hs    = (ushort*)(ws + 1048576);      // 134.2 MB fp16 [B*T, 256]
    if (ws_size < (size_t)135266304) return;      // ws too small -> recognizable absmax fail

    k_conv   <<<256, 256, 0, stream>>>(W1, W2, embed, W, W1h, W2b, Eb, Wh);
    k_proj   <<<256, 256, 0, stream>>>(embed, W_in, proj);
    k_recur  <<<256, 512, 0, stream>>>(idx, Wh, proj, hs);
    k_readout<<<2048, 512, 0, stream>>>(hs, W1h, W2b, Eb, b1, b2, gamma, beta, (float*)d_out);
}

// Round 17
// 384.997 us; speedup vs baseline: 1.3534x; 1.3534x over previous
//
#include <hip/hip_runtime.h>
#include <cstdint>

typedef __attribute__((ext_vector_type(8))) short short8;
typedef __attribute__((ext_vector_type(4))) float f32x4;

__device__ __forceinline__ ushort f2bf(float x){
    uint32_t u = __float_as_uint(x);
    u = (u + 0x7FFFu + ((u >> 16) & 1u)) >> 16;
    return (ushort)u;
}
__device__ __forceinline__ ushort f2h(float x){
    _Float16 h = (_Float16)x;
    return __builtin_bit_cast(ushort, h);
}

// -------- kernel 1: weight conversion (fp16 W + W1, bf16 W2 + embed) ------
__global__ void k_conv(const float* __restrict__ W1, const float* __restrict__ W2,
                       const float* __restrict__ Emb, const float* __restrict__ W,
                       ushort* __restrict__ W1h, ushort* __restrict__ W2b,
                       ushort* __restrict__ Eb, ushort* __restrict__ Wh){
    int i = blockIdx.x * 256 + threadIdx.x;   // grid 256 -> 65536
    W1h[i] = f2h(W1[i]);
    W2b[i] = f2bf(W2[i]);
    Eb[i]  = f2bf(Emb[i]);
    Wh[i]  = f2h(W[i]);
}

// -------- kernel 2: proj[v][h] = sum_e embed[v,e]*W_in[h,e]  (fp32) -------
__global__ void k_proj(const float* __restrict__ emb, const float* __restrict__ Win,
                       float* __restrict__ proj){
    __shared__ __align__(16) float se[256];
    int v = blockIdx.x, h = threadIdx.x;
    se[h] = emb[v*256 + h];
    __syncthreads();
    const float* wr = Win + h*256;
    float a0=0.f,a1=0.f,a2=0.f,a3=0.f;
    #pragma unroll
    for (int e = 0; e < 256; e += 4){
        float4 w = *(const float4*)(wr + e);
        a0 = fmaf(w.x, se[e+0], a0);
        a1 = fmaf(w.y, se[e+1], a1);
        a2 = fmaf(w.z, se[e+2], a2);
        a3 = fmaf(w.w, se[e+3], a3);
    }
    proj[v*256 + h] = (a0+a1)+(a2+a3);
}

// ------------- kernel 3: ESN recurrence via MFMA, fp16 W+state ------------
// 256 blocks = (segment s in [0,32)) x (batch group pg in [0,8)), 1 block/CU.
// Segment s writes t in [64s, 64s+64); s>0 starts from h=0 at
// t0 = max(0, 64s-128); warmup=128 HW-verified (rounds 13/14, absmax at
// fp16 floor). Critical path 192 steps @ ~676ns/step (round 14: ~130us).
__global__ __launch_bounds__(512, 2) void k_recur(const int* __restrict__ idx,
        const ushort* Wh, const float* proj, ushort* hs){
    __shared__ __align__(16) char Hl[2][8192];   // fp16 H[16][256], dbuf, swizzled
    const int tid  = threadIdx.x;
    const int wid  = tid >> 6;
    const int lane = tid & 63;
    const int lr   = lane & 15;        // batch col / A-row-in-tile
    const int lg   = lane >> 4;
    const int seg  = blockIdx.x >> 3;  // time segment 0..31
    const int pg   = blockIdx.x & 7;   // batch group 0..7
    const int t0   = (64*seg - 128 > 0) ? (64*seg - 128) : 0;
    const int t1   = 64*seg + 64;
    const int tw   = 64*seg;           // first written step

    // A-frags: W rows for tiles n0=2*wid, n1=2*wid+1 (fp16, 16 frags = 64 VGPR)
    short8 A0[8], A1[8];
    {
        const char* wb = (const char*)Wh + (32*wid + lr)*512 + lg*16;
        #pragma unroll
        for (int kk = 0; kk < 8; ++kk){
            A0[kk] = __builtin_bit_cast(short8, *(const uint4*)(wb + kk*64));
            A1[kk] = __builtin_bit_cast(short8, *(const uint4*)(wb + 16*512 + kk*64));
        }
    }

    char* Hb = &Hl[0][0];
    *(uint4*)(Hb + tid*16) = uint4{0,0,0,0};     // zero buffer 0 (8 KB)
    __syncthreads();

    const int mybat = pg*16 + lr;
    const int64_t idxbase = (int64_t)mybat * 2048;
    ushort* hsrow = hs + (size_t)mybat * 2048 * 256;
    const int hd0 = 32*wid + lg*4;               // tile0 quad base hdim
    const int hd1 = hd0 + 16;

    float hp0[4] = {0.f,0.f,0.f,0.f}, hp1[4] = {0.f,0.f,0.f,0.f};

    // prologue: u for t0, token for t0+1
    int tok  = idx[idxbase + t0];
    int tok2 = idx[idxbase + ((t0+1 < 2048) ? t0+1 : 2047)];
    f32x4 u0 = *(const f32x4*)(proj + tok*256 + hd0);
    f32x4 u1 = *(const f32x4*)(proj + tok*256 + hd1);

#define STEP(T, RO, WO)                                                        \
    {                                                                          \
        int tok3 = idx[idxbase + (((T)+2 < 2048) ? (T)+2 : 2047)];             \
        f32x4 ac0 = u0, ac1 = u1;   /* C-init = input projection */            \
        f32x4 bc0 = {0.f,0.f,0.f,0.f}, bc1 = {0.f,0.f,0.f,0.f};                \
        _Pragma("unroll")                                                      \
        for (int kk = 0; kk < 4; ++kk){                                        \
            int ra = ((RO) + lr*512 + kk*64 + lg*16) ^ (lr << 4);              \
            short8 Bf = __builtin_bit_cast(short8, *(const uint4*)(Hb + ra));  \
            ac0 = __builtin_amdgcn_mfma_f32_16x16x32_f16(A0[kk], Bf, ac0, 0,0,0);\
            ac1 = __builtin_amdgcn_mfma_f32_16x16x32_f16(A1[kk], Bf, ac1, 0,0,0);\
        }                                                                      \
        _Pragma("unroll")                                                      \
        for (int kk = 4; kk < 8; ++kk){                                        \
            int ra = ((RO) + lr*512 + kk*64 + lg*16) ^ (lr << 4);              \
            short8 Bf = __builtin_bit_cast(short8, *(const uint4*)(Hb + ra));  \
            bc0 = __builtin_amdgcn_mfma_f32_16x16x32_f16(A0[kk], Bf, bc0, 0,0,0);\
            bc1 = __builtin_amdgcn_mfma_f32_16x16x32_f16(A1[kk], Bf, bc1, 0,0,0);\
        }                                                                      \
        f32x4 u0n = *(const f32x4*)(proj + tok2*256 + hd0);                    \
        f32x4 u1n = *(const f32x4*)(proj + tok2*256 + hd1);                    \
        float hn0[4], hn1[4];                                                  \
        _Pragma("unroll")                                                      \
        for (int q = 0; q < 4; ++q){                                           \
            float p0 = ac0[q] + bc0[q];                                        \
            float e0 = __builtin_amdgcn_exp2f(p0 * 2.8853900817779268f);       \
            float r0 = __builtin_amdgcn_rcpf(e0 + 1.f);                        \
            hn0[q] = fmaf(0.7f, hp0[q], fmaf(-0.6f, r0, 0.3f));                \
            hp0[q] = hn0[q];                                                   \
            float p1 = ac1[q] + bc1[q];                                        \
            float e1 = __builtin_amdgcn_exp2f(p1 * 2.8853900817779268f);       \
            float r1 = __builtin_amdgcn_rcpf(e1 + 1.f);                        \
            hn1[q] = fmaf(0.7f, hp1[q], fmaf(-0.6f, r1, 0.3f));                \
            hp1[q] = hn1[q];                                                   \
        }                                                                      \
        uint2 pk0, pk1;                                                        \
        pk0.x = __builtin_bit_cast(uint, __builtin_amdgcn_cvt_pkrtz(hn0[0], hn0[1])); \
        pk0.y = __builtin_bit_cast(uint, __builtin_amdgcn_cvt_pkrtz(hn0[2], hn0[3])); \
        pk1.x = __builtin_bit_cast(uint, __builtin_amdgcn_cvt_pkrtz(hn1[0], hn1[1])); \
        pk1.y = __builtin_bit_cast(uint, __builtin_amdgcn_cvt_pkrtz(hn1[2], hn1[3])); \
        int wa0 = ((WO) + lr*512 + hd0*2) ^ (lr << 4);                         \
        int wa1 = ((WO) + lr*512 + hd1*2) ^ (lr << 4);                         \
        *(uint2*)(Hb + wa0) = pk0;                                             \
        *(uint2*)(Hb + wa1) = pk1;                                             \
        if ((T) >= tw){                                                        \
            *(uint2*)(hsrow + (size_t)(T)*256 + hd0) = pk0;                    \
            *(uint2*)(hsrow + (size_t)(T)*256 + hd1) = pk1;                    \
        }                                                                      \
        u0 = u0n; u1 = u1n; tok2 = tok3;                                       \
        asm volatile("s_waitcnt lgkmcnt(0)\n\ts_barrier" ::: "memory");        \
    }

    for (int t = t0; t < t1; t += 2){
        STEP(t,   0,    8192);
        STEP(t+1, 8192, 0);
    }
#undef STEP
}

// ---------------- kernel 4: fused readout MLP + LN + lm_head --------------
// ROUND-14 CONFIGURATION (best measured: 241us). 2048 blocks x 128 BT-rows.
// 8 waves = (mg 0..3) x (ng 0..1): wave owns 2 m-tiles and half the n-tiles
// -> each weight-fragment ds_read feeds TWO MFMAs. Unswapped GEMM3 stores
// (4B/lane, 16 consecutive lanes = 64B segments; round 16 falsified the
// swapped float4 form: 16B at 1KB stride cost +37% WRITE amplification).
// Plain stage (global->reg->LDS inside stage()): round 16 falsified the
// double-buffered T14 split (more barriers, pinned regs, MfmaUtil fell).
__global__ __launch_bounds__(512) void k_readout(
        const ushort* __restrict__ hs,
        const ushort* __restrict__ W1h, const ushort* __restrict__ W2b,
        const ushort* __restrict__ Eb,
        const float* __restrict__ b1, const float* __restrict__ b2,
        const float* __restrict__ gamma, const float* __restrict__ beta,
        float* __restrict__ out){
    __shared__ __align__(16) char w_lds[65536];   // staged weight half: 128 rows x 256
    __shared__ __align__(16) char a_lds[65536];   // A1 / y tile: 128 rows x 256 bf16
    __shared__ __align__(16) float4 ln_lds[8][16];// LN partials per (wave, lr)

    const int tid  = threadIdx.x;
    const int wid  = tid >> 6;
    const int mg   = wid >> 1;                    // m-group: rows 32mg..32mg+32
    const int ng   = wid & 1;                     // n-half
    const int lane = tid & 63;
    const int lr   = lane & 15;
    const int lg   = lane >> 4;
    const size_t m0 = (size_t)blockIdx.x * 128;
    const int ml0  = mg*32 + lr;                  // m-tile 2mg row
    const int ml1  = ml0 + 16;                    // m-tile 2mg+1 row

    // stage a 128x256 2-byte weight half into w_lds, XOR-swizzled
    auto stage = [&](const ushort* src){
        #pragma unroll
        for (int i = 0; i < 8; ++i){
            int off = (i*512 + tid) * 16;
            uint4 v = *(const uint4*)((const char*)src + off);
            int row = off >> 9;
            *(uint4*)(w_lds + (off ^ ((row & 7) << 4))) = v;
        }
    };
    // A-fragment of staged weight, tile n, k-chunk k0
    auto wfrag = [&](int n, int k0) -> short8 {
        int row  = n*16 + lr;
        int addr = (row << 9) + k0*64 + lg*16;
        addr ^= (row & 7) << 4;
        return __builtin_bit_cast(short8, *(const uint4*)(w_lds + addr));
    };
    // fragment of a_lds at row ml, k-chunk k0
    auto afrag = [&](int ml, int k0) -> short8 {
        int addr = (ml << 9) + k0*64 + lg*16;
        addr ^= (ml & 7) << 4;
        return __builtin_bit_cast(short8, *(const uint4*)(a_lds + addr));
    };
    // write 4 consecutive e-values (8B) into a_lds[ml][ecol..ecol+3]
    auto awrite = [&](int ml, int ecol, f32x4 v){
        ushort4 pk;
        pk.x = f2bf(v[0]); pk.y = f2bf(v[1]); pk.z = f2bf(v[2]); pk.w = f2bf(v[3]);
        int addr = (ml << 9) + ecol*2;
        addr ^= (ml & 7) << 4;
        *(ushort4*)(a_lds + addr) = pk;
    };

    // ---- hs fragments for both m-tiles (fp16, 16B/lane) ----
    short8 hb0[8], hb1[8];
    {
        const char* p0 = (const char*)(hs + (m0 + ml0)*256) + lg*16;
        const char* p1 = (const char*)(hs + (m0 + ml1)*256) + lg*16;
        #pragma unroll
        for (int k0 = 0; k0 < 8; ++k0){
            hb0[k0] = __builtin_bit_cast(short8, *(const uint4*)(p0 + k0*64));
            hb1[k0] = __builtin_bit_cast(short8, *(const uint4*)(p1 + k0*64));
        }
    }

    // ================= GEMM1 (fp16): A1 = gelu(hs @ W1.T + b1) =================
    #pragma unroll
    for (int h = 0; h < 2; ++h){
        __syncthreads();
        stage(W1h + h*128*256);
        __syncthreads();
        #pragma unroll
        for (int n = 0; n < 4; ++n){
            int nt = 4*ng + n;
            int eb = h*128 + nt*16;
            float4 bi = *(const float4*)(b1 + eb + lg*4);
            f32x4 acc0 = {bi.x, bi.y, bi.z, bi.w};
            f32x4 acc1 = acc0;
            #pragma unroll
            for (int k0 = 0; k0 < 8; ++k0){
                short8 wf = wfrag(nt, k0);
                acc0 = __builtin_amdgcn_mfma_f32_16x16x32_f16(wf, hb0[k0], acc0, 0,0,0);
                acc1 = __builtin_amdgcn_mfma_f32_16x16x32_f16(wf, hb1[k0], acc1, 0,0,0);
            }
            f32x4 g0, g1;
            #pragma unroll
            for (int q = 0; q < 4; ++q){
                float x = acc0[q];
                g0[q] = 0.5f*x*(1.f + erff(x*0.70710678118654752440f));
                x = acc1[q];
                g1[q] = 0.5f*x*(1.f + erff(x*0.70710678118654752440f));
            }
            awrite(ml0, eb + lg*4, g0);
            awrite(ml1, eb + lg*4, g1);
        }
    }

    // ================= GEMM2 (bf16): o = A1 @ W2.T + b2 =================
    short8 ab0[8], ab1[8];
    __syncthreads();
    #pragma unroll
    for (int k0 = 0; k0 < 8; ++k0){ ab0[k0] = afrag(ml0, k0); ab1[k0] = afrag(ml1, k0); }
    f32x4 oacc0[8], oacc1[8];
    #pragma unroll
    for (int h = 0; h < 2; ++h){
        __syncthreads();
        stage(W2b + h*128*256);
        __syncthreads();
        #pragma unroll
        for (int n = 0; n < 4; ++n){
            int nt = 4*ng + n;
            int eb = h*128 + nt*16;
            float4 bi = *(const float4*)(b2 + eb + lg*4);
            f32x4 acc0 = {bi.x, bi.y, bi.z, bi.w};
            f32x4 acc1 = acc0;
            #pragma unroll
            for (int k0 = 0; k0 < 8; ++k0){
                short8 wf = wfrag(nt, k0);
                acc0 = __builtin_amdgcn_mfma_f32_16x16x32_bf16(wf, ab0[k0], acc0, 0,0,0);
                acc1 = __builtin_amdgcn_mfma_f32_16x16x32_bf16(wf, ab1[k0], acc1, 0,0,0);
            }
            oacc0[h*4+n] = acc0;
            oacc1[h*4+n] = acc1;
        }
    }

    // ====== LayerNorm over e2: in-wave shfl + cross-wave (ng pair) LDS ======
    {
        float s0 = 0.f, q0 = 0.f, s1 = 0.f, q1 = 0.f;
        #pragma unroll
        for (int i = 0; i < 8; ++i){
            #pragma unroll
            for (int q = 0; q < 4; ++q){
                float x = oacc0[i][q]; s0 += x; q0 += x*x;
                float y = oacc1[i][q]; s1 += y; q1 += y*y;
            }
        }
        s0 += __shfl_xor(s0, 16); q0 += __shfl_xor(q0, 16);
        s0 += __shfl_xor(s0, 32); q0 += __shfl_xor(q0, 32);
        s1 += __shfl_xor(s1, 16); q1 += __shfl_xor(q1, 16);
        s1 += __shfl_xor(s1, 32); q1 += __shfl_xor(q1, 32);
        __syncthreads();                     // all waves done reading w_lds h1
        if (lg == 0) ln_lds[wid][lr] = float4{s0, q0, s1, q1};
        __syncthreads();
        float4 pp = ln_lds[wid ^ 1][lr];
        s0 += pp.x; q0 += pp.y; s1 += pp.z; q1 += pp.w;
        float mu0   = s0 * (1.f/256.f);
        float var0  = q0 * (1.f/256.f) - mu0*mu0;
        float rstd0 = rsqrtf(var0 + 1e-5f);
        float mu1   = s1 * (1.f/256.f);
        float var1  = q1 * (1.f/256.f) - mu1*mu1;
        float rstd1 = rsqrtf(var1 + 1e-5f);
        #pragma unroll
        for (int i = 0; i < 8; ++i){
            int h = i >> 2, n = i & 3;
            int ecol = h*128 + (4*ng + n)*16 + lg*4;
            float4 g4 = *(const float4*)(gamma + ecol);
            float4 t4 = *(const float4*)(beta + ecol);
            f32x4 y0, y1;
            y0[0] = (oacc0[i][0]-mu0)*rstd0*g4.x + t4.x;
            y0[1] = (oacc0[i][1]-mu0)*rstd0*g4.y + t4.y;
            y0[2] = (oacc0[i][2]-mu0)*rstd0*g4.z + t4.z;
            y0[3] = (oacc0[i][3]-mu0)*rstd0*g4.w + t4.w;
            y1[0] = (oacc1[i][0]-mu1)*rstd1*g4.x + t4.x;
            y1[1] = (oacc1[i][1]-mu1)*rstd1*g4.y + t4.y;
            y1[2] = (oacc1[i][2]-mu1)*rstd1*g4.z + t4.z;
            y1[3] = (oacc1[i][3]-mu1)*rstd1*g4.w + t4.w;
            awrite(ml0, ecol, y0);
            awrite(ml1, ecol, y1);
        }
    }

    // ================= GEMM3 (bf16): logits = y @ embed.T =================
    __syncthreads();
    #pragma unroll
    for (int k0 = 0; k0 < 8; ++k0){ ab0[k0] = afrag(ml0, k0); ab1[k0] = afrag(ml1, k0); }
    #pragma unroll
    for (int h = 0; h < 2; ++h){
        __syncthreads();
        stage(Eb + h*128*256);
        __syncthreads();
        #pragma unroll
        for (int n = 0; n < 4; ++n){
            int nt = 4*ng + n;
            f32x4 acc0 = {0.f,0.f,0.f,0.f};
            f32x4 acc1 = acc0;
            #pragma unroll
            for (int k0 = 0; k0 < 8; ++k0){
                short8 wf = wfrag(nt, k0);
                acc0 = __builtin_amdgcn_mfma_f32_16x16x32_bf16(ab0[k0], wf, acc0, 0,0,0);
                acc1 = __builtin_amdgcn_mfma_f32_16x16x32_bf16(ab1[k0], wf, acc1, 0,0,0);
            }
            int v = h*128 + nt*16 + lr;
            float* op0 = out + (m0 + mg*32 + lg*4)*256 + v;
            op0[0]   = acc0[0];
            op0[256] = acc0[1];
            op0[512] = acc0[2];
            op0[768] = acc0[3];
            float* op1 = out + (m0 + mg*32 + 16 + lg*4)*256 + v;
            op1[0]   = acc1[0];
            op1[256] = acc1[1];
            op1[512] = acc1[2];
            op1[768] = acc1[3];
        }
    }
}

// --------------------------------------------------------------------------
extern "C" void kernel_launch(void* const* d_in, const int* in_sizes, int n_in,
                              void* d_out, int out_size, void* d_ws, size_t ws_size,
                              hipStream_t stream){
    const int*   idx   = (const int*)d_in[0];
    const float* embed = (const float*)d_in[1];
    const float* W_in  = (const float*)d_in[2];
    const float* W     = (const float*)d_in[3];
    const float* W1    = (const float*)d_in[4];
    const float* b1    = (const float*)d_in[5];
    const float* W2    = (const float*)d_in[6];
    const float* b2    = (const float*)d_in[7];
    const float* gamma = (const float*)d_in[8];
    const float* beta  = (const float*)d_in[9];

    char* ws = (char*)d_ws;
    float*  proj  = (float*)ws;                   // 256 KB fp32
    ushort* W1h   = (ushort*)(ws + 262144);       // 128 KB fp16
    ushort* W2b   = (ushort*)(ws + 393216);       // 128 KB bf16
    ushort* Eb    = (ushort*)(ws + 524288);       // 128 KB bf16
    ushort* Wh    = (ushort*)(ws + 655360);       // 128 KB fp16 W
    ushort* hs    = (ushort*)(ws + 1048576);      // 134.2 MB fp16 [B*T, 256]
    if (ws_size < (size_t)135266304) return;      // ws too small -> recognizable absmax fail

    k_conv   <<<256, 256, 0, stream>>>(W1, W2, embed, W, W1h, W2b, Eb, Wh);
    k_proj   <<<256, 256, 0, stream>>>(embed, W_in, proj);
    k_recur  <<<256, 512, 0, stream>>>(idx, Wh, proj, hs);
    k_readout<<<2048, 512, 0, stream>>>(hs, W1h, W2b, Eb, b1, b2, gamma, beta, (float*)d_out);
}